// Round 7
// baseline (19.572 us; speedup 1.0000x reference)
//
#include <hip/hip_runtime.h>
#include <hip/hip_bf16.h>

// FrameReducer: N=16, T=2048, C=512, V=500 — SINGLE fused kernel.
//
// Grid (ceil(Tp/64), N) x 1024 threads. Each block independently:
//  1. mask: t = j*1024 + tid (j<ITERS): keep = (ctc[n,t,blank] < log(0.9))
//     && (t < x_lens[n]); __ballot -> LDS smask[chunk] (u64) + wcnt[chunk].
//     (~15x redundant across blocks of same n, but the blank column is
//     L2/L3-resident: ~2MB distinct lines per sequence.)
//  2. scan: tid<64 shfl_up inclusive scan of wcnt -> pfx[1..NCHUNK]; pfx[0]=0;
//     lens = pfx[NCHUNK].
//  3. gather: wave w handles rows p = blockIdx.x*64 + pass*16 + w (4 passes).
//     p < lens: binary-search pfx for chunk, k-th-set-bit in smask -> tsrc,
//     copy 2KB row at 32B/lane. p in [lens,Tp): write zeros (harness poisons
//     d_out once, never re-poisons). Block (0,n) tid 0 writes lens_out[n].

__global__ __launch_bounds__(1024) void fused_kernel(
        const float* __restrict__ x,
        const void* __restrict__ x_lens_raw,
        const float* __restrict__ ctc,
        const int* __restrict__ blank_id_p,
        int N, int T, int V, int Tp,
        float* __restrict__ out,
        float* __restrict__ lens_out) {
    const int C = 512;
    const int n    = blockIdx.y;
    const int tid  = threadIdx.x;            // 1024 = 16 waves
    const int lane = tid & 63;
    const int wid  = tid >> 6;
    const int ITERS  = (T + 1023) >> 10;     // 2 for T=2048 (<=4 supported)
    const int NCHUNK = ITERS * 16;           // 32

    __shared__ unsigned long long smask[64];
    __shared__ int wcnt[64];
    __shared__ int pfx[65];

    // x_lens dtype detection: values in [1,T], never 0 -> int64 layout iff
    // int32 view at odd index is 0.
    const int* li = (const int*)x_lens_raw;
    long long L = (N > 1 && li[1] == 0) ? ((const long long*)x_lens_raw)[n]
                                        : (long long)li[n];
    const int blank = *blank_id_p;
    const float thr = -0.10536052f;          // float32(log(0.9))

    // ---- phase 1: mask ----
    for (int j = 0; j < ITERS; ++j) {
        int t = (j << 10) + tid;
        bool keep = false;
        if (t < T) {
            float v = ctc[((long long)n * T + t) * V + blank];
            keep = (v < thr) && ((long long)t < L);
        }
        unsigned long long bal = __ballot(keep);
        if (lane == 0) {
            smask[j * 16 + wid] = bal;
            wcnt[j * 16 + wid]  = __popcll(bal);
        }
    }
    __syncthreads();

    // ---- phase 2: scan (64-entry shfl_up, once per block) ----
    if (tid < 64) {
        int c = tid;
        int incl = (c < NCHUNK) ? wcnt[c] : 0;
        #pragma unroll
        for (int d = 1; d < 64; d <<= 1) {
            int o = __shfl_up(incl, d, 64);
            if (lane >= d) incl += o;
        }
        if (c < NCHUNK) pfx[c + 1] = incl;
        if (c == 0) pfx[0] = 0;
    }
    __syncthreads();
    const int lens = pfx[NCHUNK];
    if (blockIdx.x == 0 && tid == 0) lens_out[n] = (float)lens;

    // ---- phase 3: gather (16 waves x 4 passes = 64 rows/block) ----
    for (int pass = 0; pass < 4; ++pass) {
        int p = blockIdx.x * 64 + pass * 16 + wid;   // wave-uniform
        if (p >= Tp) break;

        float4 a = make_float4(0.f, 0.f, 0.f, 0.f);
        float4 b = a;
        if (p < lens) {
            int lo = 0, hi = NCHUNK;                 // largest c: pfx[c] <= p
            while (hi - lo > 1) {
                int mid = (lo + hi) >> 1;
                if (pfx[mid] <= p) lo = mid; else hi = mid;
            }
            int r = p - pfx[lo];
            unsigned long long m = smask[lo];
            int base = 0;
            #pragma unroll
            for (int w = 32; w >= 1; w >>= 1) {
                int cnt = __popcll(m & ((1ull << w) - 1ull));
                if (r >= cnt) { r -= cnt; m >>= w; base += w; }
            }
            int tsrc = (lo << 6) + base;
            const float4* src = (const float4*)(x + ((long long)n * T + tsrc) * C);
            a = src[lane * 2];
            b = src[lane * 2 + 1];
        }
        float4* dst = (float4*)(out + ((long long)n * Tp + p) * C);
        dst[lane * 2]     = a;
        dst[lane * 2 + 1] = b;
    }
}

extern "C" void kernel_launch(void* const* d_in, const int* in_sizes, int n_in,
                              void* d_out, int out_size, void* d_ws, size_t ws_size,
                              hipStream_t stream) {
    const float* x        = (const float*)d_in[0];
    const void*  x_lens   = d_in[1];
    const float* ctc      = (const float*)d_in[2];
    const int*   blank_id = (const int*)d_in[3];

    const int N = in_sizes[1];               // 16
    const int C = 512;
    const int V = 500;
    const int T = in_sizes[0] / (N * C);     // 2048
    const int Tp = (out_size - N) / (N * C); // T'

    float* out      = (float*)d_out;                   // [N][Tp][C]
    float* lens_out = out + (long long)N * Tp * C;     // [N] float

    dim3 grid((Tp + 63) / 64, N);
    fused_kernel<<<grid, 1024, 0, stream>>>(x, x_lens, ctc, blank_id,
                                            N, T, V, Tp, out, lens_out);
}

// Round 9
// 16.893 us; speedup vs baseline: 1.1586x; 1.1586x over previous
//
#include <hip/hip_runtime.h>
#include <hip/hip_bf16.h>

// FrameReducer: N=16, T=2048, C=512, V=500 — two dispatches (best structure, R3)
// + non-temporal output stores (via clang ext_vector_type, not HIP float4:
// __builtin_nontemporal_store rejects the HIP_vector_type wrapper class).
//
// Kernel 1 (compact): N blocks x 1024 threads. keep[t] = (ctc[n,t,blank] <
//   log(0.9)) && (t < x_lens[n]); wave ballots -> chunk counts in LDS ->
//   thread-0 exclusive scan (32 entries, once per block) -> stable idx emit.
//   Writes lens[n] and float lens tail of d_out.
// Kernel 2 (gather): grid (ceil(Tp*128/256), N), 256 thr, one 16B vec/thread.
//   blockIdx.y = n -> no integer division. Each 64-lane wave covers half of
//   one row -> lens/idx are wave-uniform scalar loads. Output stores are
//   non-temporal: out is write-once, never re-read -> skip cache allocation.
//   Zero tail rows written every call (harness poisons d_out once only).

typedef float f32x4 __attribute__((ext_vector_type(4)));

__global__ void compact_kernel(const float* __restrict__ ctc,
                               const void* __restrict__ x_lens_raw,
                               const int* __restrict__ blank_id_p,
                               int T, int V, int N,
                               int* __restrict__ idx,
                               int* __restrict__ lens,
                               float* __restrict__ lens_out) {
    const int n    = blockIdx.x;
    const int tid  = threadIdx.x;          // 1024 threads = 16 waves
    const int lane = tid & 63;
    const int wid  = tid >> 6;
    const int ITERS = (T + 1023) >> 10;    // 2 for T=2048
    const int NCHUNK = ITERS * 16;         // 32

    __shared__ int wcnt[64];
    __shared__ int pfx[65];

    // x_lens dtype detection: values in [1,T], never 0 -> int64 layout iff
    // int32 view at odd index is 0.
    const int* li = (const int*)x_lens_raw;
    long long L;
    if (N > 1 && li[1] == 0) {
        L = ((const long long*)x_lens_raw)[n];
    } else {
        L = (long long)li[n];
    }

    const int blank = *blank_id_p;
    const float thr = -0.10536052f;        // float32(log(0.9))

    unsigned long long bal[4];
    #pragma unroll
    for (int j = 0; j < 4; ++j) bal[j] = 0ull;

    for (int j = 0; j < ITERS; ++j) {
        int t = (j << 10) + tid;
        bool keep = false;
        if (t < T) {
            float v = ctc[((long long)n * T + t) * V + blank];
            keep = (v < thr) && ((long long)t < L);
        }
        bal[j] = __ballot(keep);
        if (lane == 0) wcnt[j * 16 + wid] = __popcll(bal[j]);
    }
    __syncthreads();

    if (tid == 0) {
        int acc = 0;
        for (int c = 0; c < NCHUNK; ++c) { pfx[c] = acc; acc += wcnt[c]; }
        pfx[NCHUNK] = acc;
        lens[n] = acc;
        __builtin_nontemporal_store((float)acc, lens_out + n);
    }
    __syncthreads();

    int* my_idx = idx + (long long)n * T;
    for (int j = 0; j < ITERS; ++j) {
        int t = (j << 10) + tid;
        unsigned long long b = bal[j];
        if (b & (1ull << lane)) {
            int rank = __popcll(b & ((1ull << lane) - 1ull));
            my_idx[pfx[j * 16 + wid] + rank] = t;
        }
    }
}

__global__ __launch_bounds__(256) void gather_kernel(
        const f32x4* __restrict__ x,
        const int* __restrict__ idx,
        const int* __restrict__ lens,
        f32x4* __restrict__ out,
        int Tp, int T, int f4_per_seq) {
    const int n   = blockIdx.y;
    const int gid = blockIdx.x * 256 + threadIdx.x;   // f4 index within sequence
    if (gid >= f4_per_seq) return;
    const int p  = gid >> 7;                          // 128 f4 per row (C=512)
    const int c4 = gid & 127;

    f32x4 v = (f32x4)0.f;
    if (p < lens[n]) {                                // wave-uniform scalar
        int tsrc = idx[n * T + p];                    // wave-uniform scalar
        v = x[((long long)(n * T + tsrc) << 7) + c4];
    }
    __builtin_nontemporal_store(v, out + ((long long)n * Tp << 7) + gid);
}

extern "C" void kernel_launch(void* const* d_in, const int* in_sizes, int n_in,
                              void* d_out, int out_size, void* d_ws, size_t ws_size,
                              hipStream_t stream) {
    const float* x        = (const float*)d_in[0];
    const void*  x_lens   = d_in[1];
    const float* ctc      = (const float*)d_in[2];
    const int*   blank_id = (const int*)d_in[3];

    const int N = in_sizes[1];               // 16
    const int C = 512;
    const int V = 500;
    const int T = in_sizes[0] / (N * C);     // 2048
    const int Tp = (out_size - N) / (N * C); // T'

    int* idx  = (int*)d_ws;                  // [N][T]
    int* lens = idx + (long long)N * T;      // [N]

    float* out      = (float*)d_out;                   // [N][Tp][C]
    float* lens_out = out + (long long)N * Tp * C;     // [N] float

    compact_kernel<<<N, 1024, 0, stream>>>(ctc, x_lens, blank_id, T, V, N,
                                           idx, lens, lens_out);

    const int f4_per_seq = Tp * (C / 4);     // Tp*128
    dim3 ggrid((f4_per_seq + 255) / 256, N);
    gather_kernel<<<ggrid, 256, 0, stream>>>((const f32x4*)x, idx, lens,
                                             (f32x4*)out, Tp, T, f4_per_seq);
}